// Round 3
// baseline (4414.302 us; speedup 1.0000x reference)
//
#include <hip/hip_runtime.h>
#include <hip/hip_bf16.h>
#include <cstdint>

// LSTM (relu activations), B=128 T=256 F=4 H=1024, gate order i,f,g,o.
// v4: wave-autonomous. 8 clusters (bid&7 -> XCD) x 16 rows; 32 WGs/cluster x
// 32 units; each WAVE owns 8 units x 16 rows over FULL K=1024.
//  * B tiles pack 2 gates x 8 units per 16-col MFMA tile: bfrag[32 kk][2 tiles]
//    (256 VGPR, persistent). Gate completion via one __shfl_xor(.,8).
//  * NO LDS, NO __syncthreads in the time loop: zero intra-WG coupling.
//    Each wave: poll -> load A (dbuf'd 8-kk groups) -> 64 MFMA -> shuffle ->
//    epilogue -> bf16 sc1 store -> vmcnt(0) -> publish own flag.
//  * flags: per-wave, 128/cluster; poll = one 8B agent load per lane.
//  * h exchange: bf16 in d_ws (fresh address per step, flag-gated, sc1
//    write-through). fp32 out[] stores are plain writebacks after publish.
// Fallback template<0>: fp32 exchange through out[] (sc1) if ws too small.

#define B_SZ   128
#define T_SZ   256
#define H_SZ   1024
#define G_SZ   4096   // 4*H
#define ULD    130    // init staging leading dim (shorts)

typedef __attribute__((ext_vector_type(8))) short short8;
typedef __attribute__((ext_vector_type(4))) float f32x4;

__device__ __forceinline__ short f2bf(float f) {
    union { float f; unsigned u; } a; a.f = f;
    unsigned r = a.u + 0x7fffu + ((a.u >> 16) & 1u);   // RNE
    return (short)(r >> 16);
}

__device__ __forceinline__ float sigmoidf_(float x) {
    return 1.0f / (1.0f + __expf(-x));
}

// 8 fp32 -> short8 bf16 (round half-up via +0x8000, pack hi16 pairs with v_perm)
__device__ __forceinline__ short8 pack8(f32x4 a, f32x4 b) {
    union { f32x4 v; unsigned u[4]; } ua, ub; ua.v = a; ub.v = b;
    union { short8 s; unsigned d[4]; } r;
    r.d[0] = __builtin_amdgcn_perm(ua.u[1] + 0x8000u, ua.u[0] + 0x8000u, 0x07060302u);
    r.d[1] = __builtin_amdgcn_perm(ua.u[3] + 0x8000u, ua.u[2] + 0x8000u, 0x07060302u);
    r.d[2] = __builtin_amdgcn_perm(ub.u[1] + 0x8000u, ub.u[0] + 0x8000u, 0x07060302u);
    r.d[3] = __builtin_amdgcn_perm(ub.u[3] + 0x8000u, ub.u[2] + 0x8000u, 0x07060302u);
    return r.s;
}

#define LOAD_AF(dst, G) do { _Pragma("unroll")                                  \
    for (int kk2 = 0; kk2 < 8; ++kk2)                                           \
        dst[kk2] = *(const short8*)(abase + ((G) * 8 + kk2) * 32); } while (0)

#define LOAD_AF32(dst, G) do { _Pragma("unroll")                                \
    for (int kk2 = 0; kk2 < 8; ++kk2) {                                         \
        const float* p_ = abasef + ((G) * 8 + kk2) * 32;                        \
        f32x4 lo_ = *(const f32x4*)p_;                                          \
        f32x4 hi_ = *(const f32x4*)(p_ + 4);                                    \
        dst[kk2] = pack8(lo_, hi_); } } while (0)

#define MFMA_AF(src, G) do { _Pragma("unroll")                                  \
    for (int kk2 = 0; kk2 < 8; ++kk2) {                                         \
        acc0 = __builtin_amdgcn_mfma_f32_16x16x32_bf16(                         \
            src[kk2], bfrag[(G) * 8 + kk2][0], acc0, 0, 0, 0);                  \
        acc1 = __builtin_amdgcn_mfma_f32_16x16x32_bf16(                         \
            src[kk2], bfrag[(G) * 8 + kk2][1], acc1, 0, 0, 0); } } while (0)

template<int BF16EX>
__global__ __launch_bounds__(256, 1)
void lstm_persistent(const float* __restrict__ x, const float* __restrict__ W,
                     const float* __restrict__ U, const float* __restrict__ bias,
                     float* __restrict__ out, unsigned* __restrict__ flags,
                     short* __restrict__ ex)
{
    __shared__ __align__(16) short Ust[256 * ULD];   // init staging only (66.5KB)

    const int tid  = threadIdx.x;
    const int bid  = blockIdx.x;
    const int cl   = bid & 7;     // cluster 0..7 -> rows cl*16..+16 (XCD-local intent)
    const int jbb  = bid >> 3;    // 0..31 -> units jbb*32..+32
    const int wv   = tid >> 6;    // wave 0..3 -> units jbb*32 + wv*8 .. +8
    const int lane = tid & 63;
    const int q    = lane >> 4;   // quad 0..3
    const int n    = lane & 15;

    // ---------- init: persistent B fragments, full K=1024 per wave ----------
    // tile j (0/1), col c: gate = j*2 + (c>>3), unit = jbb*32 + wv*8 + (c&7)
    short8 bfrag[32][2];
    #pragma unroll
    for (int kc = 0; kc < 4; ++kc) {
        const int kbase = kc * 256;
        for (int i = tid; i < 256 * 128; i += 256) {
            int k = i >> 7, cf = i & 127;
            int wvs = cf >> 5, rem = cf & 31, js = rem >> 4, cc = rem & 15;
            int gcol = (js * 2 + (cc >> 3)) * 1024 + jbb * 32 + wvs * 8 + (cc & 7);
            Ust[k * ULD + cf] = f2bf(U[(size_t)(kbase + k) * G_SZ + gcol]);
        }
        __syncthreads();
        #pragma unroll
        for (int kk = 0; kk < 8; ++kk)
            #pragma unroll
            for (int j = 0; j < 2; ++j) {
                short8 bb;
                #pragma unroll
                for (int jj = 0; jj < 8; ++jj)
                    bb[jj] = Ust[(kk * 32 + q * 8 + jj) * ULD + wv * 32 + j * 16 + n];
                bfrag[kc * 8 + kk][j] = bb;
            }
        __syncthreads();
    }

    // ---------- per-thread constants ----------
    const int u    = jbb * 32 + wv * 8 + (n & 7);   // my output unit
    const bool hi  = (lane & 8) != 0;               // gate-half / row-half split
    const int rg0  = cl * 16 + q * 4 + (hi ? 2 : 0);
    const int rg1  = rg0 + 1;
    float Wr[4][4], br[4];
    #pragma unroll
    for (int g = 0; g < 4; ++g) {
        br[g] = bias[g * 1024 + u];
        #pragma unroll
        for (int f = 0; f < 4; ++f)
            Wr[g][f] = W[(size_t)f * G_SZ + g * 1024 + u];
    }
    float cs0 = 0.f, cs1 = 0.f;

    const int arow = cl * 16 + n;                   // A-frag row (per lane)
    const unsigned long long* pollp =
        (const unsigned long long*)(flags + cl * 128) + lane;  // 2 flags / lane
    unsigned* pubp = flags + cl * 128 + jbb * 4 + wv;

    // ---------- time loop: NO barriers, waves fully decoupled ----------
    for (int t = 0; t < T_SZ; ++t) {
        f32x4 xv0 = *(const f32x4*)(x + ((size_t)rg0 * T_SZ + t) * 4);
        f32x4 xv1 = *(const f32x4*)(x + ((size_t)rg1 * T_SZ + t) * 4);

        f32x4 acc0 = (f32x4){0.f, 0.f, 0.f, 0.f};
        f32x4 acc1 = (f32x4){0.f, 0.f, 0.f, 0.f};

        if (t > 0) {
            // wait for ALL 128 producer waves of my cluster to finish step t-1
            for (;;) {
                unsigned long long v = __hip_atomic_load(pollp, __ATOMIC_RELAXED,
                                                         __HIP_MEMORY_SCOPE_AGENT);
                bool ok = ((unsigned)v >= (unsigned)t) &&
                          ((unsigned)(v >> 32) >= (unsigned)t);
                if (__all((int)ok)) break;
                __builtin_amdgcn_s_sleep(2);
            }
            __atomic_signal_fence(__ATOMIC_ACQUIRE);  // compiler-only ordering

            short8 afA[8], afB[8];
            if (BF16EX) {
                const short* abase = ex +
                    ((size_t)arow * T_SZ + (t - 1)) * H_SZ + q * 8;
                LOAD_AF(afA, 0); LOAD_AF(afB, 1);
                MFMA_AF(afA, 0); LOAD_AF(afA, 2);
                MFMA_AF(afB, 1); LOAD_AF(afB, 3);
                MFMA_AF(afA, 2); MFMA_AF(afB, 3);
            } else {
                const float* abasef = out +
                    ((size_t)arow * T_SZ + (t - 1)) * H_SZ + q * 8;
                LOAD_AF32(afA, 0); LOAD_AF32(afB, 1);
                MFMA_AF(afA, 0);   LOAD_AF32(afA, 2);
                MFMA_AF(afB, 1);   LOAD_AF32(afB, 3);
                MFMA_AF(afA, 2);   MFMA_AF(afB, 3);
            }
        }

        // gate completion: partner lane (lane^8) holds the other two gates
        float p0[4], p1[4];
        #pragma unroll
        for (int v = 0; v < 4; ++v) {
            p0[v] = __shfl_xor(acc0[v], 8);
            p1[v] = __shfl_xor(acc1[v], 8);
        }

        // lo-lanes (hi=0): own acc = gates i,g (rows v=0,1); partner = f,o.
        // hi-lanes: own acc = gates f,o (rows v=2,3); partner = i,g.
        float hh[2];
        #pragma unroll
        for (int s = 0; s < 2; ++s) {
            float zi = hi ? p0[2 + s] : acc0[s];
            float zf = hi ? acc0[2 + s] : p0[s];
            float zg = hi ? p1[2 + s] : acc1[s];
            float zo = hi ? acc1[2 + s] : p1[s];
            const f32x4 xv = s ? xv1 : xv0;
            zi += xv[0]*Wr[0][0] + xv[1]*Wr[0][1] + xv[2]*Wr[0][2] + xv[3]*Wr[0][3] + br[0];
            zf += xv[0]*Wr[1][0] + xv[1]*Wr[1][1] + xv[2]*Wr[1][2] + xv[3]*Wr[1][3] + br[1];
            zg += xv[0]*Wr[2][0] + xv[1]*Wr[2][1] + xv[2]*Wr[2][2] + xv[3]*Wr[2][3] + br[2];
            zo += xv[0]*Wr[3][0] + xv[1]*Wr[3][1] + xv[2]*Wr[3][2] + xv[3]*Wr[3][3] + br[3];
            float ig = sigmoidf_(zi), fg = sigmoidf_(zf);
            float gg = fmaxf(zg, 0.f), og = sigmoidf_(zo);
            float cprev = s ? cs1 : cs0;
            float cnew  = fg * cprev + ig * gg;
            if (s == 0) cs0 = cnew; else cs1 = cnew;
            hh[s] = og * fmaxf(cnew, 0.f);
        }

        const size_t ob0 = ((size_t)rg0 * T_SZ + t) * H_SZ + u;
        const size_t ob1 = ((size_t)rg1 * T_SZ + t) * H_SZ + u;

        if (BF16EX) {
            // pack unit pairs (lanes n, n+1) -> one dword sc1 store per row
            float nb0 = __shfl_down(hh[0], 1);
            float nb1 = __shfl_down(hh[1], 1);
            if ((n & 1) == 0) {
                unsigned d0 = (unsigned)(unsigned short)f2bf(hh[0]) |
                              ((unsigned)(unsigned short)f2bf(nb0) << 16);
                unsigned d1 = (unsigned)(unsigned short)f2bf(hh[1]) |
                              ((unsigned)(unsigned short)f2bf(nb1) << 16);
                __hip_atomic_store((unsigned*)&ex[ob0], d0, __ATOMIC_RELAXED,
                                   __HIP_MEMORY_SCOPE_AGENT);
                __hip_atomic_store((unsigned*)&ex[ob1], d1, __ATOMIC_RELAXED,
                                   __HIP_MEMORY_SCOPE_AGENT);
            }
        } else {
            __hip_atomic_store((unsigned*)&out[ob0], __float_as_uint(hh[0]),
                               __ATOMIC_RELAXED, __HIP_MEMORY_SCOPE_AGENT);
            __hip_atomic_store((unsigned*)&out[ob1], __float_as_uint(hh[1]),
                               __ATOMIC_RELAXED, __HIP_MEMORY_SCOPE_AGENT);
        }

        if (t != T_SZ - 1) {
            // my exchange stores acked at LLC -> publish my wave's flag
            asm volatile("s_waitcnt vmcnt(0)" ::: "memory");
            if (lane == 0)
                __hip_atomic_store(pubp, (unsigned)(t + 1),
                                   __ATOMIC_RELAXED, __HIP_MEMORY_SCOPE_AGENT);
        }

        if (BF16EX) {
            // fp32 output: plain writeback, off the critical ack path
            out[ob0] = hh[0];
            out[ob1] = hh[1];
        }

        if (t == T_SZ - 1) {
            float* hlast = out + (size_t)B_SZ * T_SZ * H_SZ;
            float* clast = hlast + (size_t)B_SZ * H_SZ;
            hlast[(size_t)rg0 * H_SZ + u] = hh[0];
            hlast[(size_t)rg1 * H_SZ + u] = hh[1];
            clast[(size_t)rg0 * H_SZ + u] = cs0;
            clast[(size_t)rg1 * H_SZ + u] = cs1;
        }
    }
}

extern "C" void kernel_launch(void* const* d_in, const int* in_sizes, int n_in,
                              void* d_out, int out_size, void* d_ws, size_t ws_size,
                              hipStream_t stream) {
    const float* x    = (const float*)d_in[0];  // [128][256][4]
    const float* W    = (const float*)d_in[1];  // [4][4096]
    const float* U    = (const float*)d_in[2];  // [1024][4096]
    const float* bias = (const float*)d_in[3];  // [4096]
    float* out = (float*)d_out;                 // [128][256][1024] ++ h_last ++ c_last

    unsigned* flags = (unsigned*)d_ws;          // [8 cl][32 wg][4 wave] step flags
    short* ex = (short*)((char*)d_ws + 4096);   // bf16 h exchange [128][256][1024]

    // zero the flags (ws is poisoned 0xAA before every timed launch)
    hipMemsetAsync(d_ws, 0, 4096, stream);

    const size_t need = 4096 + (size_t)B_SZ * T_SZ * H_SZ * sizeof(short);
    if (ws_size >= need) {
        hipLaunchKernelGGL((lstm_persistent<1>), dim3(256), dim3(256), 0, stream,
                           x, W, U, bias, out, flags, ex);
    } else {
        hipLaunchKernelGGL((lstm_persistent<0>), dim3(256), dim3(256), 0, stream,
                           x, W, U, bias, out, flags, ex);
    }
}

// Round 7
// 1668.051 us; speedup vs baseline: 2.6464x; 2.6464x over previous
//
#include <hip/hip_runtime.h>
#include <hip/hip_bf16.h>
#include <cstdint>

// LSTM (relu activations), B=128 T=256 F=4 H=1024, gate order i,f,g,o.
// Persistent kernel: 256 WGs = 4 row-blocks (32 rows) x 64 hidden-blocks (16 units).
// v8 = R1 (1557us, green) + two audited deltas:
//  (A) init staging padded to ULD=130 shorts/row: the bfrag gather's dword-bank
//      becomes q*8 + (..)>>1 -> per-q disjoint bank octets -> conflict-free.
//      (R1's 1.73e7 SQ_LDS_BANK_CONFLICT was ENTIRELY this gather; ULD=64 made
//      the bank independent of q -> 8-way. Fix verified =0 in v4.)
//  (B) publish path shortened: sc1 ex stores -> vmcnt(0) -> flag -> THEN plain
//      fp32 out stores (they ack lazily; kernel-end release flushes them).
// Everything else is R1-verbatim: bf16 exchange in d_ws (fresh address per
// step, flag-gated, sc1 write-through); per-WAVE flags (producer publishes
// after its own vmcnt(0), consumer wave polls the 64 producer-wave flags of
// its K slice); zpart double-buffered [blk][q][n][v] (b128 writes 2-way,
// scalar reads 2-way); ONE __syncthreads per step.
// Fallback template<0>: fp32 exchange through out[] (sc1) if ws too small.

#define B_SZ   128
#define T_SZ   256
#define H_SZ   1024
#define G_SZ   4096   // 4*H
#define ULD    130    // init staging leading dim (shorts): conflict-free gather

typedef __attribute__((ext_vector_type(8))) short short8;
typedef __attribute__((ext_vector_type(4))) float f32x4;
typedef __attribute__((ext_vector_type(2))) float f32x2;

__device__ __forceinline__ short f2bf(float f) {
    union { float f; unsigned u; } a; a.f = f;
    unsigned r = a.u + 0x7fffu + ((a.u >> 16) & 1u);   // RNE
    return (short)(r >> 16);
}

__device__ __forceinline__ float sigmoidf_(float x) {
    return 1.0f / (1.0f + __expf(-x));
}

// 8 fp32 -> short8 bf16 (round half-up via +0x8000, pack hi16 pairs with v_perm)
__device__ __forceinline__ short8 pack8(f32x4 a, f32x4 b) {
    union { f32x4 v; unsigned u[4]; } ua, ub; ua.v = a; ub.v = b;
    union { short8 s; unsigned d[4]; } r;
    r.d[0] = __builtin_amdgcn_perm(ua.u[1] + 0x8000u, ua.u[0] + 0x8000u, 0x07060302u);
    r.d[1] = __builtin_amdgcn_perm(ua.u[3] + 0x8000u, ua.u[2] + 0x8000u, 0x07060302u);
    r.d[2] = __builtin_amdgcn_perm(ub.u[1] + 0x8000u, ub.u[0] + 0x8000u, 0x07060302u);
    r.d[3] = __builtin_amdgcn_perm(ub.u[3] + 0x8000u, ub.u[2] + 0x8000u, 0x07060302u);
    return r.s;
}

template<int BF16EX>
__global__ __launch_bounds__(256, 1)
void lstm_persistent(const float* __restrict__ x, const float* __restrict__ W,
                     const float* __restrict__ U, const float* __restrict__ bias,
                     float* __restrict__ out, unsigned* __restrict__ flags,
                     short* __restrict__ ex)
{
    __shared__ __align__(16) char smem[66560];
    short* Ust   = (short*)smem;          // init staging: [256 k][130] bf16 (66560B)
    float* zpA   = (float*)smem;          // step partials buf 0 (32768B)
    float* zpB   = (float*)(smem + 32768);// buf 1

    const int tid  = threadIdx.x;
    const int bid  = blockIdx.x;
    const int rb   = bid >> 6;    // row block 0..3  (rows rb*32 .. +32)
    const int jb   = bid & 63;    // hidden block 0..63 (units jb*16 .. +16)
    const int w    = tid >> 6;    // wave 0..3 -> K slice [w*256, w*256+256)
    const int lane = tid & 63;
    const int q    = lane >> 4;   // quad 0..3
    const int n    = lane & 15;

    // ---------- init: build persistent B fragments from U (fp32 -> bf16) ----------
    short8 bfrag[8][4];           // [kk (32-k chunk within wave slice)][gate]
    for (int kc = 0; kc < 4; ++kc) {
        const int kbase = kc * 256;
        for (int i = tid; i < 256 * 64; i += 256) {
            int k = i >> 6, col = i & 63;
            int gcol = (col >> 4) * 1024 + jb * 16 + (col & 15);
            Ust[k * ULD + col] = f2bf(U[(size_t)(kbase + k) * G_SZ + gcol]);
        }
        __syncthreads();
        if (w == kc) {
            #pragma unroll
            for (int kk = 0; kk < 8; ++kk) {
                #pragma unroll
                for (int g = 0; g < 4; ++g) {
                    short8 bb;
                    #pragma unroll
                    for (int jj = 0; jj < 8; ++jj)
                        bb[jj] = Ust[(kk * 32 + q * 8 + jj) * ULD + g * 16 + n];
                    bfrag[kk][g] = bb;
                }
            }
        }
        __syncthreads();
    }

    // ---------- per-thread epilogue constants ----------
    const int row_l  = tid >> 4;          // 0..15
    const int hid_l  = tid & 15;
    const int hid_g  = jb * 16 + hid_l;
    const int row_g0 = rb * 32 + row_l;   // pair 0 (mt=0)
    const int row_g1 = row_g0 + 16;       // pair 1 (mt=1)
    const int qr = row_l >> 2, vr = row_l & 3;
    float Wr[4][4], br[4];
    #pragma unroll
    for (int g = 0; g < 4; ++g) {
        br[g] = bias[g * 1024 + hid_g];
        #pragma unroll
        for (int f = 0; f < 4; ++f)
            Wr[g][f] = W[(size_t)f * G_SZ + g * 1024 + hid_g];
    }
    float c0 = 0.f, c1 = 0.f;

    const int arow0 = tid >= 0 ? rb * 32 + n : 0;   // A-frag rows (mt 0/1 add 0/16)
    const int krow  = w * 256 + q * 8;
    // per-wave flags: flags[rb*256 + jb*4 + wave] = #steps produced by that wave
    const unsigned* pollp = flags + rb * 256 + w * 64 + lane;   // 64 producer-waves of my K slice
    unsigned* pubp = flags + rb * 256 + jb * 4 + w;

    // ---------- time loop ----------
    for (int t = 0; t < T_SZ; ++t) {
        // x inputs (independent of h; issue early)
        f32x4 xv0 = *(const f32x4*)(x + ((size_t)row_g0 * T_SZ + t) * 4);
        f32x4 xv1 = *(const f32x4*)(x + ((size_t)row_g1 * T_SZ + t) * 4);

        // A fragments: h_{t-1}
        short8 af[8][2];
        if (t == 0) {
            short8 z = {};
            #pragma unroll
            for (int kk = 0; kk < 8; ++kk) { af[kk][0] = z; af[kk][1] = z; }
        } else {
            // per-wave poll: wait until the 64 producer-waves covering my K slice
            // have published step t (value == number of steps produced)
            for (;;) {
                unsigned v = __hip_atomic_load(pollp, __ATOMIC_RELAXED,
                                               __HIP_MEMORY_SCOPE_AGENT);
                if (__all((int)(v >= (unsigned)t))) break;
                __builtin_amdgcn_s_sleep(2);
            }
            __atomic_signal_fence(__ATOMIC_ACQUIRE);  // compiler-only ordering

            if (BF16EX) {
                #pragma unroll
                for (int kk = 0; kk < 8; ++kk) {
                    #pragma unroll
                    for (int mt = 0; mt < 2; ++mt) {
                        const short* p = ex +
                            ((size_t)(arow0 + mt * 16) * T_SZ + (t - 1)) * H_SZ +
                            krow + kk * 32;
                        af[kk][mt] = *(const short8*)p;
                    }
                }
            } else {
                #pragma unroll
                for (int kk = 0; kk < 8; ++kk) {
                    #pragma unroll
                    for (int mt = 0; mt < 2; ++mt) {
                        const float* p = out +
                            ((size_t)(arow0 + mt * 16) * T_SZ + (t - 1)) * H_SZ +
                            krow + kk * 32;
                        f32x4 lo = *(const f32x4*)p;
                        f32x4 hi = *(const f32x4*)(p + 4);
                        af[kk][mt] = pack8(lo, hi);
                    }
                }
            }
        }

        f32x4 acc[2][4];
        #pragma unroll
        for (int mt = 0; mt < 2; ++mt)
            #pragma unroll
            for (int g = 0; g < 4; ++g)
                acc[mt][g] = (f32x4){0.f, 0.f, 0.f, 0.f};

        #pragma unroll
        for (int kk = 0; kk < 8; ++kk)
            #pragma unroll
            for (int mt = 0; mt < 2; ++mt)
                #pragma unroll
                for (int g = 0; g < 4; ++g)
                    acc[mt][g] = __builtin_amdgcn_mfma_f32_16x16x32_bf16(
                        af[kk][mt], bfrag[kk][g], acc[mt][g], 0, 0, 0);

        // K-split partials -> LDS, layout [blk][q][n][v]: contiguous b128 writes
        // (2-way, free), scalar 2-way reads. Double-buffered on t&1.
        float* zp = (t & 1) ? zpB : zpA;
        #pragma unroll
        for (int mt = 0; mt < 2; ++mt)
            #pragma unroll
            for (int g = 0; g < 4; ++g)
                *(f32x4*)&zp[(((w * 2 + mt) * 4 + g) * 4 + q) * 64 + n * 4] =
                    acc[mt][g];
        __syncthreads();   // single barrier per step (write -> read, dbuf'd)

        // ---------- epilogue: sum partials, add x*W+b, gates, state update ----------
        float hn0, hn1;
        {
            float z[4];
            #pragma unroll
            for (int g = 0; g < 4; ++g) {
                float s = br[g];
                #pragma unroll
                for (int ww = 0; ww < 4; ++ww)
                    s += zp[(((ww * 2 + 0) * 4 + g) * 4 + qr) * 64 + hid_l * 4 + vr];
                s += xv0[0] * Wr[g][0] + xv0[1] * Wr[g][1] +
                     xv0[2] * Wr[g][2] + xv0[3] * Wr[g][3];
                z[g] = s;
            }
            float ig = sigmoidf_(z[0]), fg = sigmoidf_(z[1]);
            float gg = fmaxf(z[2], 0.f), og = sigmoidf_(z[3]);
            c0 = fg * c0 + ig * gg;
            hn0 = og * fmaxf(c0, 0.f);
        }
        {
            float z[4];
            #pragma unroll
            for (int g = 0; g < 4; ++g) {
                float s = br[g];
                #pragma unroll
                for (int ww = 0; ww < 4; ++ww)
                    s += zp[(((ww * 2 + 1) * 4 + g) * 4 + qr) * 64 + hid_l * 4 + vr];
                s += xv1[0] * Wr[g][0] + xv1[1] * Wr[g][1] +
                     xv1[2] * Wr[g][2] + xv1[3] * Wr[g][3];
                z[g] = s;
            }
            float ig = sigmoidf_(z[0]), fg = sigmoidf_(z[1]);
            float gg = fmaxf(z[2], 0.f), og = sigmoidf_(z[3]);
            c1 = fg * c1 + ig * gg;
            hn1 = og * fmaxf(c1, 0.f);
        }

        const size_t ob0 = ((size_t)row_g0 * T_SZ + t) * H_SZ + hid_g;
        const size_t ob1 = ((size_t)row_g1 * T_SZ + t) * H_SZ + hid_g;

        if (BF16EX) {
            // bf16 exchange: pair lanes pack 2 units -> u32, sc1 write-through.
            float o0 = __shfl_down(hn0, 1);
            float o1 = __shfl_down(hn1, 1);
            if ((hid_l & 1) == 0) {
                unsigned w0 = (unsigned)(unsigned short)f2bf(hn0) |
                              ((unsigned)(unsigned short)f2bf(o0) << 16);
                unsigned w1 = (unsigned)(unsigned short)f2bf(hn1) |
                              ((unsigned)(unsigned short)f2bf(o1) << 16);
                __hip_atomic_store((unsigned*)&ex[ob0], w0, __ATOMIC_RELAXED,
                                   __HIP_MEMORY_SCOPE_AGENT);
                __hip_atomic_store((unsigned*)&ex[ob1], w1, __ATOMIC_RELAXED,
                                   __HIP_MEMORY_SCOPE_AGENT);
            }
            // (B) publish FIRST: vmcnt(0) drains only the sc1 ex stores here
            if (t != T_SZ - 1) {
                asm volatile("s_waitcnt vmcnt(0)" ::: "memory");
                if (lane == 0)
                    __hip_atomic_store(pubp, (unsigned)(t + 1),
                                       __ATOMIC_RELAXED, __HIP_MEMORY_SCOPE_AGENT);
            }
            // fp32 output: plain cached writeback, off the critical ack path
            out[ob0] = hn0;
            out[ob1] = hn1;
        } else {
            __hip_atomic_store((unsigned*)&out[ob0], __float_as_uint(hn0),
                               __ATOMIC_RELAXED, __HIP_MEMORY_SCOPE_AGENT);
            __hip_atomic_store((unsigned*)&out[ob1], __float_as_uint(hn1),
                               __ATOMIC_RELAXED, __HIP_MEMORY_SCOPE_AGENT);
            if (t != T_SZ - 1) {
                asm volatile("s_waitcnt vmcnt(0)" ::: "memory");
                if (lane == 0)
                    __hip_atomic_store(pubp, (unsigned)(t + 1),
                                       __ATOMIC_RELAXED, __HIP_MEMORY_SCOPE_AGENT);
            }
        }

        if (t == T_SZ - 1) {
            float* hlast = out + (size_t)B_SZ * T_SZ * H_SZ;
            float* clast = hlast + (size_t)B_SZ * H_SZ;
            hlast[(size_t)row_g0 * H_SZ + hid_g] = hn0;
            hlast[(size_t)row_g1 * H_SZ + hid_g] = hn1;
            clast[(size_t)row_g0 * H_SZ + hid_g] = c0;
            clast[(size_t)row_g1 * H_SZ + hid_g] = c1;
        }
    }
}

extern "C" void kernel_launch(void* const* d_in, const int* in_sizes, int n_in,
                              void* d_out, int out_size, void* d_ws, size_t ws_size,
                              hipStream_t stream) {
    const float* x    = (const float*)d_in[0];  // [128][256][4]
    const float* W    = (const float*)d_in[1];  // [4][4096]
    const float* U    = (const float*)d_in[2];  // [1024][4096]
    const float* bias = (const float*)d_in[3];  // [4096]
    float* out = (float*)d_out;                 // [128][256][1024] ++ h_last ++ c_last

    unsigned* flags = (unsigned*)d_ws;          // [4 rb][64 jb][4 wave] step flags
    short* ex = (short*)((char*)d_ws + 4096);   // bf16 h exchange [128][256][1024]

    // zero the flags (ws is poisoned 0xAA before every timed launch)
    hipMemsetAsync(d_ws, 0, 4096, stream);

    const size_t need = 4096 + (size_t)B_SZ * T_SZ * H_SZ * sizeof(short);
    if (ws_size >= need) {
        hipLaunchKernelGGL((lstm_persistent<1>), dim3(256), dim3(256), 0, stream,
                           x, W, U, bias, out, flags, ex);
    } else {
        hipLaunchKernelGGL((lstm_persistent<0>), dim3(256), dim3(256), 0, stream,
                           x, W, U, bias, out, flags, ex);
    }
}